// Round 1
// baseline (63915.051 us; speedup 1.0000x reference)
//
#include <hip/hip_runtime.h>
#include <stdint.h>

// Problem dims
#define Bb 128
#define Tt 512
#define Hh 1024
#define Ss 128
#define Kk 64
#define HID 512
#define G3 3072
#define Dd 1152
#define LSTR 72   // LDS row stride in bf16 elems: 144B -> 2-way bank conflicts only (free)

typedef short bf16x8 __attribute__((ext_vector_type(8)));
typedef float f32x4 __attribute__((ext_vector_type(4)));
#define MFMA16 __builtin_amdgcn_mfma_f32_16x16x32_bf16

__device__ __forceinline__ unsigned short f2bf(float f) {
  union { float f; unsigned u; } v; v.f = f;
  unsigned u = v.u;
  u += 0x7fffu + ((u >> 16) & 1u);
  return (unsigned short)(u >> 16);
}
__device__ __forceinline__ float sigm(float x) { return 1.f / (1.f + __expf(-x)); }
__device__ __forceinline__ float tanh_f(float x) {
  x = fminf(15.f, fmaxf(-15.f, x));
  float e = __expf(2.f * x);
  return (e - 1.f) / (e + 1.f);
}

// ---- sync primitives (cooperative launch guarantees co-residency) ----
// __syncthreads drains vmcnt(0) per thread (stores are in L2); tid0's
// __threadfence (agent scope) then publishes to the coherence point.
__device__ __forceinline__ void fence_release_add(int* p) {
  __syncthreads();
  if (threadIdx.x == 0) {
    __threadfence();
    __hip_atomic_fetch_add(p, 1, __ATOMIC_RELEASE, __HIP_MEMORY_SCOPE_AGENT);
  }
}
__device__ __forceinline__ void spin_ge(int* p, int target) {
  __syncthreads();
  if (threadIdx.x == 0) {
    while (__hip_atomic_load(p, __ATOMIC_ACQUIRE, __HIP_MEMORY_SCOPE_AGENT) < target)
      __builtin_amdgcn_s_sleep(2);
  }
  __syncthreads();
}
__device__ __forceinline__ void gridbar(int* bar, int gen) {
  __syncthreads();
  if (threadIdx.x == 0) {
    __threadfence();
    __hip_atomic_fetch_add(bar, 1, __ATOMIC_ACQ_REL, __HIP_MEMORY_SCOPE_AGENT);
    const int tgt = 256 * gen;
    while (__hip_atomic_load(bar, __ATOMIC_ACQUIRE, __HIP_MEMORY_SCOPE_AGENT) < tgt)
      __builtin_amdgcn_s_sleep(2);
  }
  __syncthreads();
}

// ---- prep kernels: weight conversion / reorg ----
__global__ void __launch_bounds__(256) prep_convert(const float* Whh, const float* Wih,
    const float* W1, const float* W2,
    unsigned short* WhhB, unsigned short* WXB, unsigned short* W1B, unsigned short* W2B) {
  const int n0 = G3 * Hh;
  const int n1 = n0 + G3 * Hh;
  const int n2 = n1 + HID * Hh;
  const int n3 = n2 + Kk * HID;
  for (int i = blockIdx.x * 256 + threadIdx.x; i < n3; i += gridDim.x * 256) {
    if (i < n0) WhhB[i] = f2bf(Whh[i]);
    else if (i < n1) { int j = i - n0; int n = j >> 10, k = j & 1023; WXB[j] = f2bf(Wih[n * Dd + k]); }
    else if (i < n2) { int j = i - n1; W1B[j] = f2bf(W1[j]); }
    else { int j = i - n2; W2B[j] = f2bf(W2[j]); }
  }
}

// Mt[n][kk] = sum_s E[kk][s] * Wih[n][1024+s]   (folds E @ Wih_emb^T)
__global__ void __launch_bounds__(256) prep_mt(const float* Wih, const float* E, unsigned short* MtB) {
  int gid = blockIdx.x * 256 + threadIdx.x;
  if (gid >= G3 * Kk) return;
  int n = gid >> 6, kk = gid & 63;
  const float* wp = Wih + (size_t)n * Dd + Hh;
  const float* ep = E + kk * Ss;
  float s = 0.f;
  for (int t = 0; t < Ss; ++t) s += wp[t] * ep[t];
  MtB[n * Kk + kk] = f2bf(s);
}

// ---- role bodies ----

// A-role: compute h_t. blocks 0..127: mh = bid>>6 rows, jg = bid&63 -> 16 j-cols x 3 gates.
__device__ __forceinline__ void a_role(int t, int bid, const float* init_state, const float* b_ih,
    const float* b_hh, const unsigned short* WhhB, const unsigned short* MtB,
    float* h32, unsigned short* hbf, const float* gix, const float* lbuf,
    int* ctrl, unsigned short* sA, unsigned short* sB, unsigned short* sS) {
  const int tid = threadIdx.x;
  const int wv = tid >> 6, ln = tid & 63;
  const int mh = bid >> 6, jg = bid & 63;
  const int m0 = mh * 64, j0 = jg * 16;
  const int al = ln & 15, q = ln >> 4;
  const int koff = q * 8;

  f32x4 accR = {0,0,0,0}, accZ = {0,0,0,0}, accNH = {0,0,0,0}, accNS = {0,0,0,0};

  if (t > 0) {
    const unsigned short* hb = hbf + ((t - 1) & 1) * (Bb * Hh);
    for (int kc = 0; kc < 16; ++kc) {
      __syncthreads();
      for (int ch = tid; ch < 512; ch += 256) {          // A: 64 rows x 64 k
        int r = ch >> 3, c8 = (ch & 7) * 8;
        *(uint4*)&sA[r * LSTR + c8] = *(const uint4*)(hb + (m0 + r) * Hh + kc * 64 + c8);
      }
      for (int ch = tid; ch < 384; ch += 256) {          // B: 48 rows (16 per gate) x 64 k
        int r = ch >> 3, c8 = (ch & 7) * 8;
        int g = r >> 4, rr = r & 15;
        *(uint4*)&sB[r * LSTR + c8] = *(const uint4*)(WhhB + (g * Hh + j0 + rr) * Hh + kc * 64 + c8);
      }
      __syncthreads();
#pragma unroll
      for (int ks = 0; ks < 2; ++ks) {
        bf16x8 af  = *(bf16x8*)&sA[(wv * 16 + al) * LSTR + ks * 32 + koff];
        bf16x8 b0  = *(bf16x8*)&sB[(al) * LSTR + ks * 32 + koff];
        bf16x8 b1v = *(bf16x8*)&sB[(16 + al) * LSTR + ks * 32 + koff];
        bf16x8 b2v = *(bf16x8*)&sB[(32 + al) * LSTR + ks * 32 + koff];
        accR  = MFMA16(af, b0,  accR, 0, 0, 0);
        accZ  = MFMA16(af, b1v, accZ, 0, 0, 0);
        accNH = MFMA16(af, b2v, accNH, 0, 0, 0);
      }
    }
  }

  // logits_{t-1} -> softmax -> state (bf16, into sS)
  spin_ge(&ctrl[4], 8 * t);
  if (tid < 64) {
    const int m = m0 + tid;
    if (t == 0) {
      const float* is = init_state + m * Kk;
      for (int k = 0; k < Kk; ++k) sS[tid * LSTR + k] = f2bf(is[k]);
    } else {
      const float* lr = lbuf + ((t - 1) & 1) * (Bb * Kk) + m * Kk;
      float sum = 0.f;
      for (int k = 0; k < Kk; ++k) {
        float x = fminf(10.f, fmaxf(-10.f, lr[k]));
        sum += __expf(x);
      }
      float inv = 1.f / sum;
      for (int k = 0; k < Kk; ++k) {
        float x = fminf(10.f, fmaxf(-10.f, lr[k]));
        sS[tid * LSTR + k] = f2bf(__expf(x) * inv);
      }
    }
  }
  __syncthreads();
  // state k-iter: B = Mt rows (state contribution; r/z fold, n kept separate)
  for (int ch = tid; ch < 384; ch += 256) {
    int r = ch >> 3, c8 = (ch & 7) * 8;
    int g = r >> 4, rr = r & 15;
    *(uint4*)&sB[r * LSTR + c8] = *(const uint4*)(MtB + (g * Hh + j0 + rr) * Kk + c8);
  }
  __syncthreads();
#pragma unroll
  for (int ks = 0; ks < 2; ++ks) {
    bf16x8 af  = *(bf16x8*)&sS[(wv * 16 + al) * LSTR + ks * 32 + koff];
    bf16x8 b0  = *(bf16x8*)&sB[(al) * LSTR + ks * 32 + koff];
    bf16x8 b1v = *(bf16x8*)&sB[(16 + al) * LSTR + ks * 32 + koff];
    bf16x8 b2v = *(bf16x8*)&sB[(32 + al) * LSTR + ks * 32 + koff];
    accR  = MFMA16(af, b0,  accR, 0, 0, 0);
    accZ  = MFMA16(af, b1v, accZ, 0, 0, 0);
    accNS = MFMA16(af, b2v, accNS, 0, 0, 0);
  }

  // gi_x_t ready? (only a real wait at t=0; afterwards barrier-ordered)
  spin_ge(&ctrl[1], 96 * (t + 1));

  const float* gx = gix + (t & 1) * (Bb * G3);
  const float* hp = h32 + ((t + 1) & 1) * (Bb * Hh);
  float* hc = h32 + (t & 1) * (Bb * Hh);
  unsigned short* hbc = hbf + (t & 1) * (Bb * Hh);
  const int j = j0 + al;
  const float bir = b_ih[j], biz = b_ih[Hh + j], bin_ = b_ih[2 * Hh + j];
  const float bhr = b_hh[j], bhz = b_hh[Hh + j], bhn = b_hh[2 * Hh + j];
#pragma unroll
  for (int i = 0; i < 4; ++i) {
    const int m = m0 + wv * 16 + q * 4 + i;
    float gr  = accR[i] + gx[m * G3 + j] + bir + bhr;
    float gz  = accZ[i] + gx[m * G3 + Hh + j] + biz + bhz;
    float hn  = accNH[i] + bhn;
    float in_ = accNS[i] + gx[m * G3 + 2 * Hh + j] + bin_;
    float r = sigm(gr), z = sigm(gz);
    float n = tanh_f(in_ + r * hn);
    float hprev = (t > 0) ? hp[m * Hh + j] : 0.f;
    float hnew = (1.f - z) * n + z * hprev;
    hc[m * Hh + j] = hnew;
    hbc[m * Hh + j] = f2bf(hnew);
  }
}

// X-role: gi_x_{tt} = x_tt @ W_ihx^T. blocks 128..223 (xg 0..95), 32 cols each.
__device__ __forceinline__ void x_role(int tt, int xg, const float* ctx, unsigned short* xbf,
    const unsigned short* WXB, float* gix, int* ctrl,
    unsigned short* sA, unsigned short* sB) {
  const int tid = threadIdx.x;
  const int wv = tid >> 6, ln = tid & 63;
  const int al = ln & 15, q = ln >> 4, koff = q * 8;
  const int c0 = xg * 32;

  // cooperative fp32->bf16 conversion of x_tt
  unsigned short* xb = xbf + (tt & 1) * (Bb * Hh);
  {
    int i4beg = xg * 342;
    int i4end = i4beg + 342; if (i4end > 32768) i4end = 32768;
    for (int i4 = i4beg + tid; i4 < i4end; i4 += 256) {
      int e = i4 * 4;
      int m = e >> 10, hh = e & 1023;
      const float4 v = *(const float4*)(ctx + (size_t)m * (Tt * Hh) + (size_t)tt * Hh + hh);
      ushort4 o;
      o.x = f2bf(v.x); o.y = f2bf(v.y); o.z = f2bf(v.z); o.w = f2bf(v.w);
      *(ushort4*)(xb + e) = o;
    }
  }
  fence_release_add(&ctrl[2]);
  spin_ge(&ctrl[2], 96 * (tt + 1));

  f32x4 a00 = {0,0,0,0}, a01 = {0,0,0,0}, a10 = {0,0,0,0}, a11 = {0,0,0,0};
  for (int kc = 0; kc < 16; ++kc) {
    __syncthreads();
    for (int ch = tid; ch < 1024; ch += 256) {           // A: 128 rows x 64 k
      int r = ch >> 3, c8 = (ch & 7) * 8;
      *(uint4*)&sA[r * LSTR + c8] = *(const uint4*)(xb + r * Hh + kc * 64 + c8);
    }
    {
      int r = tid >> 3, c8 = (tid & 7) * 8;              // B: 32 rows x 64 k
      *(uint4*)&sB[r * LSTR + c8] = *(const uint4*)(WXB + (c0 + r) * Hh + kc * 64 + c8);
    }
    __syncthreads();
#pragma unroll
    for (int ks = 0; ks < 2; ++ks) {
      bf16x8 a0  = *(bf16x8*)&sA[(wv * 32 + al) * LSTR + ks * 32 + koff];
      bf16x8 a1  = *(bf16x8*)&sA[(wv * 32 + 16 + al) * LSTR + ks * 32 + koff];
      bf16x8 b0  = *(bf16x8*)&sB[al * LSTR + ks * 32 + koff];
      bf16x8 b1v = *(bf16x8*)&sB[(16 + al) * LSTR + ks * 32 + koff];
      a00 = MFMA16(a0, b0,  a00, 0, 0, 0);
      a01 = MFMA16(a0, b1v, a01, 0, 0, 0);
      a10 = MFMA16(a1, b0,  a10, 0, 0, 0);
      a11 = MFMA16(a1, b1v, a11, 0, 0, 0);
    }
  }
  float* go = gix + (tt & 1) * (Bb * G3);
#pragma unroll
  for (int i = 0; i < 4; ++i) {
    int mb = wv * 32 + q * 4 + i;
    go[mb * G3 + c0 + al] = a00[i];
    go[mb * G3 + c0 + 16 + al] = a01[i];
    go[(mb + 16) * G3 + c0 + al] = a10[i];
    go[(mb + 16) * G3 + c0 + 16 + al] = a11[i];
  }
  fence_release_add(&ctrl[1]);
}

// AL-role: a_s = tanh(h_s W1^T + b1), then 8 blocks compute logits_s (writes d_out + lbuf).
__device__ __forceinline__ void al_role(int s, int ag, const unsigned short* hbf,
    const unsigned short* W1B, const unsigned short* W2B, const float* b1, const float* b2,
    unsigned short* abf, float* lbuf, float* dout, int* ctrl,
    unsigned short* sA, unsigned short* sB) {
  const int tid = threadIdx.x;
  const int wv = tid >> 6, ln = tid & 63;
  const int al = ln & 15, q = ln >> 4, koff = q * 8;
  const int c0 = ag * 16;
  const unsigned short* hb = hbf + (s & 1) * (Bb * Hh);

  f32x4 aa0 = {0,0,0,0}, aa1 = {0,0,0,0};
  for (int kc = 0; kc < 16; ++kc) {
    __syncthreads();
    for (int ch = tid; ch < 1024; ch += 256) {           // A: 128 rows x 64 k
      int r = ch >> 3, c8 = (ch & 7) * 8;
      *(uint4*)&sA[r * LSTR + c8] = *(const uint4*)(hb + r * Hh + kc * 64 + c8);
    }
    if (tid < 128) {                                     // B: 16 rows x 64 k
      int r = tid >> 3, c8 = (tid & 7) * 8;
      *(uint4*)&sB[r * LSTR + c8] = *(const uint4*)(W1B + (c0 + r) * Hh + kc * 64 + c8);
    }
    __syncthreads();
#pragma unroll
    for (int ks = 0; ks < 2; ++ks) {
      bf16x8 a0 = *(bf16x8*)&sA[(wv * 32 + al) * LSTR + ks * 32 + koff];
      bf16x8 a1 = *(bf16x8*)&sA[(wv * 32 + 16 + al) * LSTR + ks * 32 + koff];
      bf16x8 b0 = *(bf16x8*)&sB[al * LSTR + ks * 32 + koff];
      aa0 = MFMA16(a0, b0, aa0, 0, 0, 0);
      aa1 = MFMA16(a1, b0, aa1, 0, 0, 0);
    }
  }
  const float b1v = b1[c0 + al];
#pragma unroll
  for (int i = 0; i < 4; ++i) {
    int mb = wv * 32 + q * 4 + i;
    abf[mb * HID + c0 + al] = f2bf(tanh_f(aa0[i] + b1v));
    abf[(mb + 16) * HID + c0 + al] = f2bf(tanh_f(aa1[i] + b1v));
  }
  fence_release_add(&ctrl[3]);

  if (ag < 8) {                                          // logits: 16 rows x 64 cols, K=512
    spin_ge(&ctrl[3], 32 * (s + 1));
    const int r0 = ag * 16;
    f32x4 lg = {0,0,0,0};
    for (int kc = 0; kc < 8; ++kc) {
      __syncthreads();
      if (tid < 128) {                                   // A: 16 rows x 64 k
        int r = tid >> 3, c8 = (tid & 7) * 8;
        *(uint4*)&sA[r * LSTR + c8] = *(const uint4*)(abf + (r0 + r) * HID + kc * 64 + c8);
      }
      for (int ch = tid; ch < 512; ch += 256) {          // B: 64 rows x 64 k
        int r = ch >> 3, c8 = (ch & 7) * 8;
        *(uint4*)&sB[r * LSTR + c8] = *(const uint4*)(W2B + r * HID + kc * 64 + c8);
      }
      __syncthreads();
#pragma unroll
      for (int ks = 0; ks < 2; ++ks) {
        bf16x8 af  = *(bf16x8*)&sA[al * LSTR + ks * 32 + koff];
        bf16x8 bf_ = *(bf16x8*)&sB[(wv * 16 + al) * LSTR + ks * 32 + koff];
        lg = MFMA16(af, bf_, lg, 0, 0, 0);
      }
    }
    const int col = wv * 16 + al;
    const float bb = b2[col];
    float* lb = lbuf + (s & 1) * (Bb * Kk);
#pragma unroll
    for (int i = 0; i < 4; ++i) {
      int row = r0 + q * 4 + i;
      float v = lg[i] + bb;
      dout[row * (Tt * Kk) + s * Kk + col] = v;
      lb[row * Kk + col] = v;
    }
    fence_release_add(&ctrl[4]);
  }
}

// ---- persistent cooperative kernel ----
__global__ void __launch_bounds__(256, 1)
seqkern(const float* ctx, const float* init_state, const float* b_ih, const float* b_hh,
        const float* b1, const float* b2, float* dout,
        const unsigned short* WhhB, const unsigned short* WXB, const unsigned short* W1B,
        const unsigned short* W2B, const unsigned short* MtB,
        float* h32, unsigned short* hbf, float* gix, unsigned short* xbf,
        unsigned short* abf, float* lbuf, int* ctrl) {
  __shared__ unsigned short sA[128 * LSTR];
  __shared__ unsigned short sB[64 * LSTR];
  __shared__ unsigned short sS[64 * LSTR];
  const int bid = blockIdx.x;

  // prologue: X blocks produce gi_x_0 (A-role t=0 spin-waits flagX>=96)
  if (bid >= 128 && bid < 224)
    x_role(0, bid - 128, ctx, xbf, WXB, gix, ctrl, sA, sB);

  for (int t = 0; t <= Tt; ++t) {
    if (bid < 128) {
      if (t < Tt)
        a_role(t, bid, init_state, b_ih, b_hh, WhhB, MtB, h32, hbf, gix, lbuf, ctrl, sA, sB, sS);
    } else if (bid < 224) {
      if (t <= Tt - 2)
        x_role(t + 1, bid - 128, ctx, xbf, WXB, gix, ctrl, sA, sB);
    } else {
      if (t >= 1)
        al_role(t - 1, bid - 224, hbf, W1B, W2B, b1, b2, abf, lbuf, dout, ctrl, sA, sB);
    }
    if (t < Tt) gridbar(&ctrl[0], t + 1);
  }
}

extern "C" void kernel_launch(void* const* d_in, const int* in_sizes, int n_in,
                              void* d_out, int out_size, void* d_ws, size_t ws_size,
                              hipStream_t stream) {
  const float* ctx        = (const float*)d_in[0];
  const float* init_state = (const float*)d_in[1];
  const float* E          = (const float*)d_in[2];
  const float* Wih        = (const float*)d_in[3];
  const float* Whh        = (const float*)d_in[4];
  const float* b_ih       = (const float*)d_in[5];
  const float* b_hh       = (const float*)d_in[6];
  const float* W1         = (const float*)d_in[7];
  const float* b1         = (const float*)d_in[8];
  const float* W2         = (const float*)d_in[9];
  const float* b2         = (const float*)d_in[10];
  float* out = (float*)d_out;
  (void)in_sizes; (void)n_in; (void)out_size; (void)ws_size;

  char* ws = (char*)d_ws;
  size_t off = 0;
  auto take = [&](size_t sz) { char* p = ws + off; off += (sz + 255) & ~(size_t)255; return p; };
  int* ctrl             = (int*)take(256);
  unsigned short* WhhB  = (unsigned short*)take((size_t)G3 * Hh * 2);
  unsigned short* WXB   = (unsigned short*)take((size_t)G3 * Hh * 2);
  unsigned short* W1B   = (unsigned short*)take((size_t)HID * Hh * 2);
  unsigned short* W2B   = (unsigned short*)take((size_t)Kk * HID * 2);
  unsigned short* MtB   = (unsigned short*)take((size_t)G3 * Kk * 2);
  float* h32            = (float*)take((size_t)2 * Bb * Hh * 4);
  unsigned short* hbf   = (unsigned short*)take((size_t)2 * Bb * Hh * 2);
  float* gix            = (float*)take((size_t)2 * Bb * G3 * 4);
  unsigned short* xbf   = (unsigned short*)take((size_t)2 * Bb * Hh * 2);
  unsigned short* abf   = (unsigned short*)take((size_t)Bb * HID * 2);
  float* lbuf           = (float*)take((size_t)2 * Bb * Kk * 4);

  hipMemsetAsync(ctrl, 0, 256, stream);
  hipLaunchKernelGGL(prep_convert, dim3(2048), dim3(256), 0, stream,
                     Whh, Wih, W1, W2, WhhB, WXB, W1B, W2B);
  hipLaunchKernelGGL(prep_mt, dim3(768), dim3(256), 0, stream, Wih, E, MtB);

  void* args[] = {(void*)&ctx, (void*)&init_state, (void*)&b_ih, (void*)&b_hh,
                  (void*)&b1, (void*)&b2, (void*)&out,
                  (void*)&WhhB, (void*)&WXB, (void*)&W1B, (void*)&W2B, (void*)&MtB,
                  (void*)&h32, (void*)&hbf, (void*)&gix, (void*)&xbf,
                  (void*)&abf, (void*)&lbuf, (void*)&ctrl};
  hipLaunchCooperativeKernel((const void*)seqkern, dim3(256), dim3(256), args, 0, stream);
}

// Round 2
// 27917.825 us; speedup vs baseline: 2.2894x; 2.2894x over previous
//
#include <hip/hip_runtime.h>
#include <stdint.h>

// Problem dims
#define Bb 128
#define Tt 512
#define Hh 1024
#define Ss 128
#define Kk 64
#define HID 512
#define G3 3072
#define Dd 1152
#define KC 256     // K-chunk per LDS stage
#define LSTRA 264  // LDS stride (bf16) for KC=256 tiles: 528B/row -> 2-way conflicts only
#define LSTRS 72   // LDS stride for 64-wide state tile

typedef short bf16x8 __attribute__((ext_vector_type(8)));
typedef float f32x4 __attribute__((ext_vector_type(4)));
#define MFMA16 __builtin_amdgcn_mfma_f32_16x16x32_bf16

// ctrl counters (monotonic): [1] x-gemm done (96/step)  [2] x-convert done (96/step)
// [3] a=tanh(hW1) done (32/step)  [4] logits+softmax done (8/step)  [5] h done (128/step)

__device__ __forceinline__ unsigned short f2bf(float f) {
  union { float f; unsigned u; } v; v.f = f;
  unsigned u = v.u;
  u += 0x7fffu + ((u >> 16) & 1u);
  return (unsigned short)(u >> 16);
}
__device__ __forceinline__ float sigm(float x) { return 1.f / (1.f + __expf(-x)); }
__device__ __forceinline__ float tanh_f(float x) {
  x = fminf(15.f, fmaxf(-15.f, x));
  float e = __expf(2.f * x);
  return (e - 1.f) / (e + 1.f);
}

// release: one RMW by tid0 (compiler emits waitcnt+L2 writeback before the add)
__device__ __forceinline__ void rel_add(int* p) {
  __syncthreads();
  if (threadIdx.x == 0)
    __hip_atomic_fetch_add(p, 1, __ATOMIC_RELEASE, __HIP_MEMORY_SCOPE_AGENT);
}
// RELAXED poll (no per-iteration cache inv!) — caller adds acq_fence() only when
// it will READ data published by the counter's producers (WAR gates skip it).
__device__ __forceinline__ void wait_ge(int* p, int target) {
  __syncthreads();
  if (threadIdx.x == 0) {
    while (__hip_atomic_load(p, __ATOMIC_RELAXED, __HIP_MEMORY_SCOPE_AGENT) < target)
      __builtin_amdgcn_s_sleep(4);
  }
  __syncthreads();
}
__device__ __forceinline__ void acq_fence() {
  __builtin_amdgcn_fence(__ATOMIC_ACQUIRE, "agent");
}

// ---- prep kernels ----
__global__ void __launch_bounds__(256) prep_convert(const float* Whh, const float* Wih,
    const float* W1, const float* W2,
    unsigned short* WhhB, unsigned short* WXB, unsigned short* W1B, unsigned short* W2B) {
  const int n0 = G3 * Hh;
  const int n1 = n0 + G3 * Hh;
  const int n2 = n1 + HID * Hh;
  const int n3 = n2 + Kk * HID;
  for (int i = blockIdx.x * 256 + threadIdx.x; i < n3; i += gridDim.x * 256) {
    if (i < n0) WhhB[i] = f2bf(Whh[i]);
    else if (i < n1) { int j = i - n0; int n = j >> 10, k = j & 1023; WXB[j] = f2bf(Wih[n * Dd + k]); }
    else if (i < n2) { int j = i - n1; W1B[j] = f2bf(W1[j]); }
    else { int j = i - n2; W2B[j] = f2bf(W2[j]); }
  }
}
__global__ void __launch_bounds__(256) prep_mt(const float* Wih, const float* E, unsigned short* MtB) {
  int gid = blockIdx.x * 256 + threadIdx.x;
  if (gid >= G3 * Kk) return;
  int n = gid >> 6, kk = gid & 63;
  const float* wp = Wih + (size_t)n * Dd + Hh;
  const float* ep = E + kk * Ss;
  float s = 0.f;
  for (int t = 0; t < Ss; ++t) s += wp[t] * ep[t];
  MtB[n * Kk + kk] = f2bf(s);
}

// ---- A role: blocks 0..127 — recurrent gates + h update ----
__device__ void a_main(int bid, const float* init_state, const float* b_ih, const float* b_hh,
    const unsigned short* WhhB, const unsigned short* MtB,
    float* h32, unsigned short* hbf, const float* gix, const unsigned short* sbuf,
    int* ctrl, unsigned short* sA, unsigned short* sB, unsigned short* sS) {
  const int tid = threadIdx.x;
  const int wv = tid >> 6, ln = tid & 63;
  const int mh = bid >> 6, jg = bid & 63;
  const int m0 = mh * 64, j0 = jg * 16;
  const int al = ln & 15, q = ln >> 4, koff = q * 8;
  const int j = j0 + al;
  const float bir = b_ih[j], biz = b_ih[Hh + j], bin_ = b_ih[2 * Hh + j];
  const float bhr = b_hh[j], bhz = b_hh[Hh + j], bhn = b_hh[2 * Hh + j];

  for (int t = 0; t < Tt; ++t) {
    f32x4 accR = {0,0,0,0}, accZ = {0,0,0,0}, accNH = {0,0,0,0}, accNS = {0,0,0,0};

    if (t > 0) {
      wait_ge(&ctrl[5], 128 * t);   // all A finished t-1 (hbf[(t-1)&1] complete)
      acq_fence();
      const unsigned short* hb = hbf + ((t - 1) & 1) * (Bb * Hh);
      for (int kc = 0; kc < 4; ++kc) {
        const int k0 = kc * KC;
        __syncthreads();
        {
          int ch = tid;
#pragma unroll
          for (int u = 0; u < 8; ++u, ch += 256) {   // A: 64 rows x 256 k
            int r = ch >> 5, c8 = (ch & 31) * 8;
            *(uint4*)&sA[r * LSTRA + c8] = *(const uint4*)(hb + (m0 + r) * Hh + k0 + c8);
          }
        }
        {
          int ch = tid;
#pragma unroll
          for (int u = 0; u < 6; ++u, ch += 256) {   // B: 48 rows (16/gate) x 256 k
            int r = ch >> 5, c8 = (ch & 31) * 8;
            int g = r >> 4, rr = r & 15;
            *(uint4*)&sB[r * LSTRA + c8] = *(const uint4*)(WhhB + (g * Hh + j0 + rr) * Hh + k0 + c8);
          }
        }
        __syncthreads();
#pragma unroll
        for (int ks = 0; ks < 8; ++ks) {
          bf16x8 af  = *(bf16x8*)&sA[(wv * 16 + al) * LSTRA + ks * 32 + koff];
          bf16x8 b0  = *(bf16x8*)&sB[(al) * LSTRA + ks * 32 + koff];
          bf16x8 b1v = *(bf16x8*)&sB[(16 + al) * LSTRA + ks * 32 + koff];
          bf16x8 b2v = *(bf16x8*)&sB[(32 + al) * LSTRA + ks * 32 + koff];
          accR  = MFMA16(af, b0,  accR, 0, 0, 0);
          accZ  = MFMA16(af, b1v, accZ, 0, 0, 0);
          accNH = MFMA16(af, b2v, accNH, 0, 0, 0);
        }
      }
    }

    // state probs for step t (softmax(logits_{t-1}) computed by logits blocks)
    if (t > 0) {
      wait_ge(&ctrl[4], 8 * t);
      acq_fence();
      const unsigned short* sb = sbuf + ((t - 1) & 1) * (Bb * Kk);
      int ch = tid;
#pragma unroll
      for (int u = 0; u < 2; ++u, ch += 256) {       // 64 rows x 64 cols bf16
        int r = ch >> 3, c8 = (ch & 7) * 8;
        *(uint4*)&sS[r * LSTRS + c8] = *(const uint4*)(sb + (m0 + r) * Kk + c8);
      }
    } else {
      __syncthreads();
      for (int e = tid; e < 4096; e += 256) {
        int r = e >> 6, k = e & 63;
        sS[r * LSTRS + k] = f2bf(init_state[(m0 + r) * Kk + k]);
      }
    }
    for (int ch = tid; ch < 384; ch += 256) {        // Mt: 48 rows x 64 cols
      int r = ch >> 3, c8 = (ch & 7) * 8;
      int g = r >> 4, rr = r & 15;
      *(uint4*)&sB[r * LSTRA + c8] = *(const uint4*)(MtB + (g * Hh + j0 + rr) * Kk + c8);
    }
    __syncthreads();
#pragma unroll
    for (int ks = 0; ks < 2; ++ks) {
      bf16x8 af  = *(bf16x8*)&sS[(wv * 16 + al) * LSTRS + ks * 32 + koff];
      bf16x8 b0  = *(bf16x8*)&sB[(al) * LSTRA + ks * 32 + koff];
      bf16x8 b1v = *(bf16x8*)&sB[(16 + al) * LSTRA + ks * 32 + koff];
      bf16x8 b2v = *(bf16x8*)&sB[(32 + al) * LSTRA + ks * 32 + koff];
      accR  = MFMA16(af, b0,  accR, 0, 0, 0);
      accZ  = MFMA16(af, b1v, accZ, 0, 0, 0);
      accNS = MFMA16(af, b2v, accNS, 0, 0, 0);
    }

    wait_ge(&ctrl[1], 96 * (t + 1));   // gi_x_t ready (pipelined X role)
    acq_fence();

    const float* gx = gix + (t & 1) * (Bb * G3);
    const float* hp = h32 + ((t + 1) & 1) * (Bb * Hh);
    float* hc = h32 + (t & 1) * (Bb * Hh);
    unsigned short* hbc = hbf + (t & 1) * (Bb * Hh);
#pragma unroll
    for (int i = 0; i < 4; ++i) {
      const int m = m0 + wv * 16 + q * 4 + i;
      float gr  = accR[i] + gx[m * G3 + j] + bir + bhr;
      float gz  = accZ[i] + gx[m * G3 + Hh + j] + biz + bhz;
      float hn  = accNH[i] + bhn;
      float in_ = accNS[i] + gx[m * G3 + 2 * Hh + j] + bin_;
      float r = sigm(gr), z = sigm(gz);
      float n = tanh_f(in_ + r * hn);
      float hprev = (t > 0) ? hp[m * Hh + j] : 0.f;
      float hnew = (1.f - z) * n + z * hprev;
      hc[m * Hh + j] = hnew;
      hbc[m * Hh + j] = f2bf(hnew);
    }
    rel_add(&ctrl[5]);
  }
}

// ---- X role: blocks 128..223 — gi_x = x_t @ W_ihx^T (2 steps ahead) ----
__device__ void x_main(int xg, const float* ctx, unsigned short* xbf,
    const unsigned short* WXB, float* gix, int* ctrl,
    unsigned short* sA, unsigned short* sB) {
  const int tid = threadIdx.x;
  const int wv = tid >> 6, ln = tid & 63;
  const int al = ln & 15, q = ln >> 4, koff = q * 8;
  const int c0 = xg * 32;

  for (int tt = 0; tt < Tt; ++tt) {
    if (tt >= 2) wait_ge(&ctrl[1], 96 * (tt - 1));   // WAR: xbf[tt&1] readers done
    unsigned short* xb = xbf + (tt & 1) * (Bb * Hh);
    {
      int i4beg = xg * 342;
      int i4end = i4beg + 342; if (i4end > 32768) i4end = 32768;
      for (int i4 = i4beg + tid; i4 < i4end; i4 += 256) {
        int e = i4 * 4;
        int m = e >> 10, hh = e & 1023;
        const float4 v = *(const float4*)(ctx + (size_t)m * (Tt * Hh) + (size_t)tt * Hh + hh);
        ushort4 o;
        o.x = f2bf(v.x); o.y = f2bf(v.y); o.z = f2bf(v.z); o.w = f2bf(v.w);
        *(ushort4*)(xb + e) = o;
      }
    }
    rel_add(&ctrl[2]);
    wait_ge(&ctrl[2], 96 * (tt + 1));
    acq_fence();

    f32x4 a00 = {0,0,0,0}, a01 = {0,0,0,0}, a10 = {0,0,0,0}, a11 = {0,0,0,0};
    for (int kc = 0; kc < 4; ++kc) {
      const int k0 = kc * KC;
      __syncthreads();
      {
        int ch = tid;
#pragma unroll
        for (int u = 0; u < 16; ++u, ch += 256) {    // A: 128 rows x 256 k
          int r = ch >> 5, c8 = (ch & 31) * 8;
          *(uint4*)&sA[r * LSTRA + c8] = *(const uint4*)(xb + r * Hh + k0 + c8);
        }
      }
      {
        int ch = tid;
#pragma unroll
        for (int u = 0; u < 4; ++u, ch += 256) {     // B: 32 rows x 256 k
          int r = ch >> 5, c8 = (ch & 31) * 8;
          *(uint4*)&sB[r * LSTRA + c8] = *(const uint4*)(WXB + (c0 + r) * Hh + k0 + c8);
        }
      }
      __syncthreads();
#pragma unroll
      for (int ks = 0; ks < 8; ++ks) {
        bf16x8 a0  = *(bf16x8*)&sA[(wv * 32 + al) * LSTRA + ks * 32 + koff];
        bf16x8 a1  = *(bf16x8*)&sA[(wv * 32 + 16 + al) * LSTRA + ks * 32 + koff];
        bf16x8 b0  = *(bf16x8*)&sB[al * LSTRA + ks * 32 + koff];
        bf16x8 b1v = *(bf16x8*)&sB[(16 + al) * LSTRA + ks * 32 + koff];
        a00 = MFMA16(a0, b0,  a00, 0, 0, 0);
        a01 = MFMA16(a0, b1v, a01, 0, 0, 0);
        a10 = MFMA16(a1, b0,  a10, 0, 0, 0);
        a11 = MFMA16(a1, b1v, a11, 0, 0, 0);
      }
    }
    if (tt >= 2) wait_ge(&ctrl[5], 128 * (tt - 1));  // WAR: gix[tt&1] consumed by A(tt-2)
    float* go = gix + (tt & 1) * (Bb * G3);
#pragma unroll
    for (int i = 0; i < 4; ++i) {
      int mb = wv * 32 + q * 4 + i;
      go[mb * G3 + c0 + al] = a00[i];
      go[mb * G3 + c0 + 16 + al] = a01[i];
      go[(mb + 16) * G3 + c0 + al] = a10[i];
      go[(mb + 16) * G3 + c0 + 16 + al] = a11[i];
    }
    rel_add(&ctrl[1]);
  }
}

// ---- AL role: blocks 224..255 — a = tanh(hW1+b1); 8 of them do logits+softmax ----
__device__ void al_main(int ag, const unsigned short* hbf,
    const unsigned short* W1B, const unsigned short* W2B, const float* b1, const float* b2,
    unsigned short* abf, unsigned short* sbuf, float* dout, int* ctrl,
    unsigned short* sA, unsigned short* sB, unsigned short* sS) {
  const int tid = threadIdx.x;
  const int wv = tid >> 6, ln = tid & 63;
  const int al = ln & 15, q = ln >> 4, koff = q * 8;
  const int c0 = ag * 16;
  const float b1v = b1[c0 + al];
  const float b2v = b2[wv * 16 + al];
  float* sE = (float*)sS;          // 16 x 68 fp32 softmax scratch
  float* sInv = (float*)(sS + 4416);

  for (int s = 0; s < Tt; ++s) {
    wait_ge(&ctrl[5], 128 * (s + 1));     // h_s complete
    acq_fence();
    if (s >= 2) wait_ge(&ctrl[4], 8 * (s - 1));  // WAR: abf[s&1] readers done
    const unsigned short* hb = hbf + (s & 1) * (Bb * Hh);
    unsigned short* ab = abf + (s & 1) * (Bb * HID);

    f32x4 aa0 = {0,0,0,0}, aa1 = {0,0,0,0};
    for (int kc = 0; kc < 4; ++kc) {
      const int k0 = kc * KC;
      __syncthreads();
      {
        int ch = tid;
#pragma unroll
        for (int u = 0; u < 16; ++u, ch += 256) {  // A: 128 rows x 256 k
          int r = ch >> 5, c8 = (ch & 31) * 8;
          *(uint4*)&sA[r * LSTRA + c8] = *(const uint4*)(hb + r * Hh + k0 + c8);
        }
      }
      {
        int ch = tid;
#pragma unroll
        for (int u = 0; u < 2; ++u, ch += 256) {   // B: 16 rows x 256 k
          int r = ch >> 5, c8 = (ch & 31) * 8;
          *(uint4*)&sB[r * LSTRA + c8] = *(const uint4*)(W1B + (c0 + r) * Hh + k0 + c8);
        }
      }
      __syncthreads();
#pragma unroll
      for (int ks = 0; ks < 8; ++ks) {
        bf16x8 a0 = *(bf16x8*)&sA[(wv * 32 + al) * LSTRA + ks * 32 + koff];
        bf16x8 a1 = *(bf16x8*)&sA[(wv * 32 + 16 + al) * LSTRA + ks * 32 + koff];
        bf16x8 b0 = *(bf16x8*)&sB[al * LSTRA + ks * 32 + koff];
        aa0 = MFMA16(a0, b0, aa0, 0, 0, 0);
        aa1 = MFMA16(a1, b0, aa1, 0, 0, 0);
      }
    }
#pragma unroll
    for (int i = 0; i < 4; ++i) {
      int mb = wv * 32 + q * 4 + i;
      ab[mb * HID + c0 + al] = f2bf(tanh_f(aa0[i] + b1v));
      ab[(mb + 16) * HID + c0 + al] = f2bf(tanh_f(aa1[i] + b1v));
    }
    rel_add(&ctrl[3]);

    if (ag < 8) {
      wait_ge(&ctrl[3], 32 * (s + 1));
      acq_fence();
      const int r0 = ag * 16;
      f32x4 lg = {0,0,0,0};
      for (int kc = 0; kc < 2; ++kc) {
        const int k0 = kc * KC;
        __syncthreads();
        {
          int ch = tid;
#pragma unroll
          for (int u = 0; u < 2; ++u, ch += 256) { // A: 16 rows x 256 k
            int r = ch >> 5, c8 = (ch & 31) * 8;
            *(uint4*)&sA[r * LSTRA + c8] = *(const uint4*)(ab + (r0 + r) * HID + k0 + c8);
          }
        }
        {
          int ch = tid;
#pragma unroll
          for (int u = 0; u < 8; ++u, ch += 256) { // B: 64 rows x 256 k
            int r = ch >> 5, c8 = (ch & 31) * 8;
            *(uint4*)&sB[r * LSTRA + c8] = *(const uint4*)(W2B + r * HID + k0 + c8);
          }
        }
        __syncthreads();
#pragma unroll
        for (int ks = 0; ks < 8; ++ks) {
          bf16x8 af  = *(bf16x8*)&sA[al * LSTRA + ks * 32 + koff];
          bf16x8 bf_ = *(bf16x8*)&sB[(wv * 16 + al) * LSTRA + ks * 32 + koff];
          lg = MFMA16(af, bf_, lg, 0, 0, 0);
        }
      }
      float vraw[4], ev[4];
#pragma unroll
      for (int i = 0; i < 4; ++i) {
        float v = lg[i] + b2v;
        vraw[i] = v;
        float c = fminf(10.f, fmaxf(-10.f, v));
        ev[i] = __expf(c);
        sE[(q * 4 + i) * 68 + (wv * 16 + al)] = ev[i];
      }
      __syncthreads();
      if (tid < 16) {
        const float* row = &sE[tid * 68];
        float sm = 0.f;
        for (int k = 0; k < 64; ++k) sm += row[k];
        sInv[tid] = 1.f / sm;
      }
      __syncthreads();
      const int col = wv * 16 + al;
      unsigned short* sb = sbuf + (s & 1) * (Bb * Kk);
#pragma unroll
      for (int i = 0; i < 4; ++i) {
        int row16 = q * 4 + i;
        int grow = r0 + row16;
        dout[grow * (Tt * Kk) + s * Kk + col] = vraw[i];
        sb[grow * Kk + col] = f2bf(ev[i] * sInv[row16]);
      }
      rel_add(&ctrl[4]);
    }
  }
}

__global__ void __launch_bounds__(256, 1)
seqkern(const float* ctx, const float* init_state, const float* b_ih, const float* b_hh,
        const float* b1, const float* b2, float* dout,
        const unsigned short* WhhB, const unsigned short* WXB, const unsigned short* W1B,
        const unsigned short* W2B, const unsigned short* MtB,
        float* h32, unsigned short* hbf, float* gix, unsigned short* xbf,
        unsigned short* abf, unsigned short* sbuf, int* ctrl) {
  extern __shared__ char smem[];
  unsigned short* sA = (unsigned short*)smem;                   // 128*264*2 = 67584
  unsigned short* sB = (unsigned short*)(smem + 67584);         // 64*264*2  = 33792
  unsigned short* sS = (unsigned short*)(smem + 101376);        // 9216
  const int bid = blockIdx.x;
  if (bid < 128)
    a_main(bid, init_state, b_ih, b_hh, WhhB, MtB, h32, hbf, gix, sbuf, ctrl, sA, sB, sS);
  else if (bid < 224)
    x_main(bid - 128, ctx, xbf, WXB, gix, ctrl, sA, sB);
  else
    al_main(bid - 224, hbf, W1B, W2B, b1, b2, abf, sbuf, dout, ctrl, sA, sB, sS);
}

extern "C" void kernel_launch(void* const* d_in, const int* in_sizes, int n_in,
                              void* d_out, int out_size, void* d_ws, size_t ws_size,
                              hipStream_t stream) {
  const float* ctx        = (const float*)d_in[0];
  const float* init_state = (const float*)d_in[1];
  const float* E          = (const float*)d_in[2];
  const float* Wih        = (const float*)d_in[3];
  const float* Whh        = (const float*)d_in[4];
  const float* b_ih       = (const float*)d_in[5];
  const float* b_hh       = (const float*)d_in[6];
  const float* W1         = (const float*)d_in[7];
  const float* b1         = (const float*)d_in[8];
  const float* W2         = (const float*)d_in[9];
  const float* b2         = (const float*)d_in[10];
  float* out = (float*)d_out;
  (void)in_sizes; (void)n_in; (void)out_size; (void)ws_size;

  char* ws = (char*)d_ws;
  size_t off = 0;
  auto take = [&](size_t sz) { char* p = ws + off; off += (sz + 255) & ~(size_t)255; return p; };
  int* ctrl             = (int*)take(256);
  unsigned short* WhhB  = (unsigned short*)take((size_t)G3 * Hh * 2);
  unsigned short* WXB   = (unsigned short*)take((size_t)G3 * Hh * 2);
  unsigned short* W1B   = (unsigned short*)take((size_t)HID * Hh * 2);
  unsigned short* W2B   = (unsigned short*)take((size_t)Kk * HID * 2);
  unsigned short* MtB   = (unsigned short*)take((size_t)G3 * Kk * 2);
  float* h32            = (float*)take((size_t)2 * Bb * Hh * 4);
  unsigned short* hbf   = (unsigned short*)take((size_t)2 * Bb * Hh * 2);
  float* gix            = (float*)take((size_t)2 * Bb * G3 * 4);
  unsigned short* xbf   = (unsigned short*)take((size_t)2 * Bb * Hh * 2);
  unsigned short* abf   = (unsigned short*)take((size_t)2 * Bb * HID * 2);
  unsigned short* sbuf  = (unsigned short*)take((size_t)2 * Bb * Kk * 2);

  hipMemsetAsync(ctrl, 0, 256, stream);
  hipLaunchKernelGGL(prep_convert, dim3(2048), dim3(256), 0, stream,
                     Whh, Wih, W1, W2, WhhB, WXB, W1B, W2B);
  hipLaunchKernelGGL(prep_mt, dim3(768), dim3(256), 0, stream, Wih, E, MtB);

  static int smem_set = 0;
  if (!smem_set) {
    hipFuncSetAttribute((const void*)seqkern,
                        hipFuncAttributeMaxDynamicSharedMemorySize, 110592);
    smem_set = 1;
  }
  void* args[] = {(void*)&ctx, (void*)&init_state, (void*)&b_ih, (void*)&b_hh,
                  (void*)&b1, (void*)&b2, (void*)&out,
                  (void*)&WhhB, (void*)&WXB, (void*)&W1B, (void*)&W2B, (void*)&MtB,
                  (void*)&h32, (void*)&hbf, (void*)&gix, (void*)&xbf,
                  (void*)&abf, (void*)&sbuf, (void*)&ctrl};
  hipLaunchCooperativeKernel((const void*)seqkern, dim3(256), dim3(256), args, 110592, stream);
}

// Round 3
// 17119.049 us; speedup vs baseline: 3.7336x; 1.6308x over previous
//
#include <hip/hip_runtime.h>
#include <stdint.h>

// Problem dims
#define Bb 128
#define Tt 512
#define Hh 1024
#define Ss 128
#define Kk 64
#define HID 512
#define G3 3072
#define Dd 1152
#define KC 256     // K-chunk per LDS stage
#define LSTRA 264  // LDS stride (bf16) for KC=256 tiles: 528B/row -> 2-way conflicts only
#define LSTRS 72   // LDS stride for 64-wide state tile

typedef short bf16x8 __attribute__((ext_vector_type(8)));
typedef float f32x4 __attribute__((ext_vector_type(4)));
typedef unsigned int u32x4v __attribute__((ext_vector_type(4)));
#define MFMA16 __builtin_amdgcn_mfma_f32_16x16x32_bf16

// ctrl counters, each padded to its own 128B line:
// CTR(1) x done (64/step)  CTR(2) x-convert done (64/step)
// CTR(3) a=tanh(hW1) done (64/step)  CTR(4) logits+softmax done (8/step)
// CTR(5) h done (128/step)
#define CTR(i) (ctrl + (i) * 32)

__device__ __forceinline__ unsigned short f2bf(float f) {
  union { float f; unsigned u; } v; v.f = f;
  unsigned u = v.u;
  u += 0x7fffu + ((u >> 16) & 1u);
  return (unsigned short)(u >> 16);
}
__device__ __forceinline__ float sigm(float x) { return 1.f / (1.f + __expf(-x)); }
__device__ __forceinline__ float tanh_f(float x) {
  x = fminf(15.f, fmaxf(-15.f, x));
  float e = __expf(2.f * x);
  return (e - 1.f) / (e + 1.f);
}

// Coherent (L1+L2-bypassing) batched loads. Self-contained: loads + vmcnt(0)
// inside one asm block so compiler vmcnt bookkeeping elsewhere stays valid.
__device__ __forceinline__ void cload8(u32x4v o[8], const void* p, int sb) {
  const char* c = (const char*)p;
  asm volatile(
    "global_load_dwordx4 %0, %8, off sc0 sc1\n\t"
    "global_load_dwordx4 %1, %9, off sc0 sc1\n\t"
    "global_load_dwordx4 %2, %10, off sc0 sc1\n\t"
    "global_load_dwordx4 %3, %11, off sc0 sc1\n\t"
    "global_load_dwordx4 %4, %12, off sc0 sc1\n\t"
    "global_load_dwordx4 %5, %13, off sc0 sc1\n\t"
    "global_load_dwordx4 %6, %14, off sc0 sc1\n\t"
    "global_load_dwordx4 %7, %15, off sc0 sc1\n\t"
    "s_waitcnt vmcnt(0)"
    : "=&v"(o[0]), "=&v"(o[1]), "=&v"(o[2]), "=&v"(o[3]),
      "=&v"(o[4]), "=&v"(o[5]), "=&v"(o[6]), "=&v"(o[7])
    : "v"(c), "v"(c + sb), "v"(c + 2 * sb), "v"(c + 3 * sb),
      "v"(c + 4 * sb), "v"(c + 5 * sb), "v"(c + 6 * sb), "v"(c + 7 * sb)
    : "memory");
}
__device__ __forceinline__ void cload2(u32x4v o[2], const void* p, int sb) {
  const char* c = (const char*)p;
  asm volatile(
    "global_load_dwordx4 %0, %2, off sc0 sc1\n\t"
    "global_load_dwordx4 %1, %3, off sc0 sc1\n\t"
    "s_waitcnt vmcnt(0)"
    : "=&v"(o[0]), "=&v"(o[1])
    : "v"(c), "v"(c + sb)
    : "memory");
}
__device__ __forceinline__ void cloadf4(float o[4], const float* p, int sb) {
  const char* c = (const char*)p;
  asm volatile(
    "global_load_dword %0, %4, off sc0 sc1\n\t"
    "global_load_dword %1, %5, off sc0 sc1\n\t"
    "global_load_dword %2, %6, off sc0 sc1\n\t"
    "global_load_dword %3, %7, off sc0 sc1\n\t"
    "s_waitcnt vmcnt(0)"
    : "=&v"(o[0]), "=&v"(o[1]), "=&v"(o[2]), "=&v"(o[3])
    : "v"(c), "v"(c + sb), "v"(c + 2 * sb), "v"(c + 3 * sb)
    : "memory");
}

// release: tid0 RMW; compiler emits buffer_wbl2 + waitcnt before the add,
// publishing this block's prior plain stores to the L3 coherence point.
__device__ __forceinline__ void rel_add(int* p) {
  __syncthreads();
  if (threadIdx.x == 0)
    __hip_atomic_fetch_add(p, 1, __ATOMIC_RELEASE, __HIP_MEMORY_SCOPE_AGENT);
}
// RELAXED poll — no cache maintenance ever. Data is read via cloadN (coherent).
__device__ __forceinline__ void wait_ge(int* p, int target) {
  __syncthreads();
  if (threadIdx.x == 0) {
    while (__hip_atomic_load(p, __ATOMIC_RELAXED, __HIP_MEMORY_SCOPE_AGENT) < target)
      __builtin_amdgcn_s_sleep(1);
  }
  __syncthreads();
}

// ---- prep kernels ----
__global__ void __launch_bounds__(256) prep_convert(const float* Whh, const float* Wih,
    const float* W1, const float* W2,
    unsigned short* WhhB, unsigned short* WXB, unsigned short* W1B, unsigned short* W2B) {
  const int n0 = G3 * Hh;
  const int n1 = n0 + G3 * Hh;
  const int n2 = n1 + HID * Hh;
  const int n3 = n2 + Kk * HID;
  for (int i = blockIdx.x * 256 + threadIdx.x; i < n3; i += gridDim.x * 256) {
    if (i < n0) WhhB[i] = f2bf(Whh[i]);
    else if (i < n1) { int j = i - n0; int n = j >> 10, k = j & 1023; WXB[j] = f2bf(Wih[n * Dd + k]); }
    else if (i < n2) { int j = i - n1; W1B[j] = f2bf(W1[j]); }
    else { int j = i - n2; W2B[j] = f2bf(W2[j]); }
  }
}
__global__ void __launch_bounds__(256) prep_mt(const float* Wih, const float* E, unsigned short* MtB) {
  int gid = blockIdx.x * 256 + threadIdx.x;
  if (gid >= G3 * Kk) return;
  int n = gid >> 6, kk = gid & 63;
  const float* wp = Wih + (size_t)n * Dd + Hh;
  const float* ep = E + kk * Ss;
  float s = 0.f;
  for (int t = 0; t < Ss; ++t) s += wp[t] * ep[t];
  MtB[n * Kk + kk] = f2bf(s);
}

// ---- A role: blocks 0..127 — recurrent gates + h update ----
__device__ void a_main(int bid, const float* init_state, const float* b_ih, const float* b_hh,
    const unsigned short* WhhB, const unsigned short* MtB,
    float* h32, unsigned short* hbf, const float* gix, const unsigned short* sbuf,
    int* ctrl, unsigned short* sA, unsigned short* sB, unsigned short* sS) {
  const int tid = threadIdx.x;
  const int wv = tid >> 6, ln = tid & 63;
  const int mh = bid >> 6, jg = bid & 63;
  const int m0 = mh * 64, j0 = jg * 16;
  const int al = ln & 15, q = ln >> 4, koff = q * 8;
  const int j = j0 + al;
  const float bir = b_ih[j], biz = b_ih[Hh + j], bin_ = b_ih[2 * Hh + j];
  const float bhr = b_hh[j], bhz = b_hh[Hh + j], bhn = b_hh[2 * Hh + j];

  for (int t = 0; t < Tt; ++t) {
    f32x4 accR = {0,0,0,0}, accZ = {0,0,0,0}, accNH = {0,0,0,0}, accNS = {0,0,0,0};

    if (t > 0) {
      wait_ge(CTR(5), 128 * t);   // all A finished t-1 (hbf[(t-1)&1] complete)
      const unsigned short* hb = hbf + ((t - 1) & 1) * (Bb * Hh);
      const int ra = tid >> 5, c8 = (tid & 31) * 8;
      for (int kc = 0; kc < 4; ++kc) {
        const int k0 = kc * KC;
        __syncthreads();
        {
          u32x4v tmp[8];                                 // A: 64 rows x 256 k, coherent
          cload8(tmp, hb + (m0 + ra) * Hh + k0 + c8, 8 * Hh * 2);
#pragma unroll
          for (int u = 0; u < 8; ++u)
            *(u32x4v*)&sA[(ra + 8 * u) * LSTRA + c8] = tmp[u];
        }
        {
          int ch = tid;
#pragma unroll
          for (int u = 0; u < 6; ++u, ch += 256) {       // B: 48 rows x 256 k, L2-resident
            int r = ch >> 5, cc = (ch & 31) * 8;
            int g = r >> 4, rr = r & 15;
            *(u32x4v*)&sB[r * LSTRA + cc] = *(const u32x4v*)(WhhB + (g * Hh + j0 + rr) * Hh + k0 + cc);
          }
        }
        __syncthreads();
#pragma unroll
        for (int ks = 0; ks < 8; ++ks) {
          bf16x8 af  = *(bf16x8*)&sA[(wv * 16 + al) * LSTRA + ks * 32 + koff];
          bf16x8 b0  = *(bf16x8*)&sB[(al) * LSTRA + ks * 32 + koff];
          bf16x8 b1v = *(bf16x8*)&sB[(16 + al) * LSTRA + ks * 32 + koff];
          bf16x8 b2v = *(bf16x8*)&sB[(32 + al) * LSTRA + ks * 32 + koff];
          accR  = MFMA16(af, b0,  accR, 0, 0, 0);
          accZ  = MFMA16(af, b1v, accZ, 0, 0, 0);
          accNH = MFMA16(af, b2v, accNH, 0, 0, 0);
        }
      }
    }

    // gi_x_t prefetch into registers (ready in steady state; off critical path)
    wait_ge(CTR(1), 64 * (t + 1));
    float gxr[4], gxz[4], gxn[4];
    {
      const float* gp = gix + (t & 1) * (Bb * G3) + (size_t)(m0 + wv * 16 + q * 4) * G3;
      cloadf4(gxr, gp + j, G3 * 4);
      cloadf4(gxz, gp + Hh + j, G3 * 4);
      cloadf4(gxn, gp + 2 * Hh + j, G3 * 4);
    }

    // state probs for step t
    __syncthreads();
    if (t > 0) {
      wait_ge(CTR(4), 8 * t);
      const unsigned short* sb = sbuf + ((t - 1) & 1) * (Bb * Kk);
      u32x4v tmp[2];                                     // 64 rows x 64 cols bf16, coherent
      cload2(tmp, sb + (m0 + (tid >> 3)) * Kk + (tid & 7) * 8, 32 * Kk * 2);
      *(u32x4v*)&sS[(tid >> 3) * LSTRS + (tid & 7) * 8] = tmp[0];
      *(u32x4v*)&sS[((tid >> 3) + 32) * LSTRS + (tid & 7) * 8] = tmp[1];
    } else {
      for (int e = tid; e < 4096; e += 256) {
        int r = e >> 6, k = e & 63;
        sS[r * LSTRS + k] = f2bf(init_state[(m0 + r) * Kk + k]);
      }
    }
    for (int ch = tid; ch < 384; ch += 256) {            // Mt: 48 rows x 64 cols, L2
      int r = ch >> 3, cc = (ch & 7) * 8;
      int g = r >> 4, rr = r & 15;
      *(u32x4v*)&sB[r * LSTRA + cc] = *(const u32x4v*)(MtB + (g * Hh + j0 + rr) * Kk + cc);
    }
    __syncthreads();
#pragma unroll
    for (int ks = 0; ks < 2; ++ks) {
      bf16x8 af  = *(bf16x8*)&sS[(wv * 16 + al) * LSTRS + ks * 32 + koff];
      bf16x8 b0  = *(bf16x8*)&sB[(al) * LSTRA + ks * 32 + koff];
      bf16x8 b1v = *(bf16x8*)&sB[(16 + al) * LSTRA + ks * 32 + koff];
      bf16x8 b2v = *(bf16x8*)&sB[(32 + al) * LSTRA + ks * 32 + koff];
      accR  = MFMA16(af, b0,  accR, 0, 0, 0);
      accZ  = MFMA16(af, b1v, accZ, 0, 0, 0);
      accNS = MFMA16(af, b2v, accNS, 0, 0, 0);
    }

    const float* hp = h32 + ((t + 1) & 1) * (Bb * Hh);
    float* hc = h32 + (t & 1) * (Bb * Hh);
    unsigned short* hbc = hbf + (t & 1) * (Bb * Hh);
#pragma unroll
    for (int i = 0; i < 4; ++i) {
      const int m = m0 + wv * 16 + q * 4 + i;
      float gr  = accR[i] + gxr[i] + bir + bhr;
      float gz  = accZ[i] + gxz[i] + biz + bhz;
      float hn  = accNH[i] + bhn;
      float in_ = accNS[i] + gxn[i] + bin_;
      float r = sigm(gr), z = sigm(gz);
      float n = tanh_f(in_ + r * hn);
      float hprev = (t > 0) ? hp[m * Hh + j] : 0.f;      // own block's prior write
      float hnew = (1.f - z) * n + z * hprev;
      hc[m * Hh + j] = hnew;
      hbc[m * Hh + j] = f2bf(hnew);
    }
    rel_add(CTR(5));
  }
}

// ---- X role: blocks 128..191 — gi_x = x_t @ W_ihx^T (1 step ahead), 48 cols each ----
__device__ void x_main(int xg, const float* ctx, unsigned short* xbf,
    const unsigned short* WXB, float* gix, int* ctrl,
    unsigned short* sA, unsigned short* sB) {
  const int tid = threadIdx.x;
  const int wv = tid >> 6, ln = tid & 63;
  const int al = ln & 15, q = ln >> 4, koff = q * 8;
  const int c0 = xg * 48;

  for (int tt = 0; tt < Tt; ++tt) {
    if (tt >= 2) wait_ge(CTR(1), 64 * (tt - 1));   // WAR: xbf[tt&1] readers done
    unsigned short* xb = xbf + (tt & 1) * (Bb * Hh);
    {
      int i4beg = xg * 512 + tid;
#pragma unroll
      for (int u = 0; u < 2; ++u) {
        int e = (i4beg + u * 256) * 4;
        int m = e >> 10, hh = e & 1023;
        const float4 v = *(const float4*)(ctx + (size_t)m * (Tt * Hh) + (size_t)tt * Hh + hh);
        ushort4 o;
        o.x = f2bf(v.x); o.y = f2bf(v.y); o.z = f2bf(v.z); o.w = f2bf(v.w);
        *(ushort4*)(xb + e) = o;
      }
    }
    rel_add(CTR(2));
    wait_ge(CTR(2), 64 * (tt + 1));

    f32x4 a00 = {0,0,0,0}, a01 = {0,0,0,0}, a02 = {0,0,0,0};
    f32x4 a10 = {0,0,0,0}, a11 = {0,0,0,0}, a12 = {0,0,0,0};
    const int ra = tid >> 5, c8 = (tid & 31) * 8;
    for (int kc = 0; kc < 4; ++kc) {
      const int k0 = kc * KC;
      __syncthreads();
      {
        u32x4v tmp[8];                                   // A: rows 0..63, coherent
        cload8(tmp, xb + ra * Hh + k0 + c8, 8 * Hh * 2);
#pragma unroll
        for (int u = 0; u < 8; ++u)
          *(u32x4v*)&sA[(ra + 8 * u) * LSTRA + c8] = tmp[u];
        u32x4v tmp2[8];                                  // A: rows 64..127
        cload8(tmp2, xb + (64 + ra) * Hh + k0 + c8, 8 * Hh * 2);
#pragma unroll
        for (int u = 0; u < 8; ++u)
          *(u32x4v*)&sA[(64 + ra + 8 * u) * LSTRA + c8] = tmp2[u];
      }
      {
        int ch = tid;
#pragma unroll
        for (int u = 0; u < 6; ++u, ch += 256) {         // B: 48 rows x 256 k, L2
          int r = ch >> 5, cc = (ch & 31) * 8;
          *(u32x4v*)&sB[r * LSTRA + cc] = *(const u32x4v*)(WXB + (c0 + r) * Hh + k0 + cc);
        }
      }
      __syncthreads();
#pragma unroll
      for (int ks = 0; ks < 8; ++ks) {
        bf16x8 a0  = *(bf16x8*)&sA[(wv * 32 + al) * LSTRA + ks * 32 + koff];
        bf16x8 a1  = *(bf16x8*)&sA[(wv * 32 + 16 + al) * LSTRA + ks * 32 + koff];
        bf16x8 b0  = *(bf16x8*)&sB[al * LSTRA + ks * 32 + koff];
        bf16x8 b1v = *(bf16x8*)&sB[(16 + al) * LSTRA + ks * 32 + koff];
        bf16x8 b2v = *(bf16x8*)&sB[(32 + al) * LSTRA + ks * 32 + koff];
        a00 = MFMA16(a0, b0,  a00, 0, 0, 0);
        a01 = MFMA16(a0, b1v, a01, 0, 0, 0);
        a02 = MFMA16(a0, b2v, a02, 0, 0, 0);
        a10 = MFMA16(a1, b0,  a10, 0, 0, 0);
        a11 = MFMA16(a1, b1v, a11, 0, 0, 0);
        a12 = MFMA16(a1, b2v, a12, 0, 0, 0);
      }
    }
    if (tt >= 2) wait_ge(CTR(5), 128 * (tt - 1));  // WAR: gix[tt&1] consumed by A(tt-2)
    float* go = gix + (tt & 1) * (Bb * G3);
#pragma unroll
    for (int i = 0; i < 4; ++i) {
      int mb = wv * 32 + q * 4 + i;
      go[mb * G3 + c0 + al] = a00[i];
      go[mb * G3 + c0 + 16 + al] = a01[i];
      go[mb * G3 + c0 + 32 + al] = a02[i];
      go[(mb + 16) * G3 + c0 + al] = a10[i];
      go[(mb + 16) * G3 + c0 + 16 + al] = a11[i];
      go[(mb + 16) * G3 + c0 + 32 + al] = a12[i];
    }
    rel_add(CTR(1));
  }
}

// ---- AL role: blocks 192..255 — a = tanh(hW1+b1) (64 blocks: 32 col-grp x 2 row-half);
//      first 8 blocks also do logits+softmax ----
__device__ void al_main(int ag, const unsigned short* hbf,
    const unsigned short* W1B, const unsigned short* W2B, const float* b1, const float* b2,
    unsigned short* abf, unsigned short* sbuf, float* dout, int* ctrl,
    unsigned short* sA, unsigned short* sB, unsigned short* sS) {
  const int tid = threadIdx.x;
  const int wv = tid >> 6, ln = tid & 63;
  const int al = ln & 15, q = ln >> 4, koff = q * 8;
  const int c0 = (ag >> 1) * 16;     // 16 a-cols
  const int rh = (ag & 1) * 64;      // row half
  const float b1v = b1[c0 + al];
  const float b2v = b2[wv * 16 + al];
  float* sE = (float*)sS;            // 16 x 68 fp32 softmax scratch
  float* sInv = (float*)(sS + 4416);

  for (int s = 0; s < Tt; ++s) {
    wait_ge(CTR(5), 128 * (s + 1));            // h_s complete
    if (s >= 2) wait_ge(CTR(4), 8 * (s - 1));  // WAR: abf[s&1] readers done
    const unsigned short* hb = hbf + (s & 1) * (Bb * Hh);
    unsigned short* ab = abf + (s & 1) * (Bb * HID);

    f32x4 aa = {0,0,0,0};
    const int ra = tid >> 5, c8 = (tid & 31) * 8;
    for (int kc = 0; kc < 4; ++kc) {
      const int k0 = kc * KC;
      __syncthreads();
      {
        u32x4v tmp[8];                                   // A: 64 rows x 256 k, coherent
        cload8(tmp, hb + (rh + ra) * Hh + k0 + c8, 8 * Hh * 2);
#pragma unroll
        for (int u = 0; u < 8; ++u)
          *(u32x4v*)&sA[(ra + 8 * u) * LSTRA + c8] = tmp[u];
      }
      {
        int ch = tid;
#pragma unroll
        for (int u = 0; u < 2; ++u, ch += 256) {         // B: 16 rows x 256 k, L2
          int r = ch >> 5, cc = (ch & 31) * 8;
          *(u32x4v*)&sB[r * LSTRA + cc] = *(const u32x4v*)(W1B + (c0 + r) * Hh + k0 + cc);
        }
      }
      __syncthreads();
#pragma unroll
      for (int ks = 0; ks < 8; ++ks) {
        bf16x8 a0 = *(bf16x8*)&sA[(wv * 16 + al) * LSTRA + ks * 32 + koff];
        bf16x8 b0 = *(bf16x8*)&sB[al * LSTRA + ks * 32 + koff];
        aa = MFMA16(a0, b0, aa, 0, 0, 0);
      }
    }
#pragma unroll
    for (int i = 0; i < 4; ++i) {
      int mb = rh + wv * 16 + q * 4 + i;
      ab[mb * HID + c0 + al] = f2bf(tanh_f(aa[i] + b1v));
    }
    rel_add(CTR(3));

    if (ag < 8) {
      wait_ge(CTR(3), 64 * (s + 1));
      const int r0 = ag * 16;
      f32x4 lg = {0,0,0,0};
      for (int kc = 0; kc < 2; ++kc) {
        const int k0 = kc * KC;
        __syncthreads();
        {
          u32x4v tmp[2];                                 // A: 16 rows x 256 k, coherent
          cload2(tmp, ab + (r0 + ra) * HID + k0 + c8, 8 * HID * 2);
          *(u32x4v*)&sA[ra * LSTRA + c8] = tmp[0];
          *(u32x4v*)&sA[(ra + 8) * LSTRA + c8] = tmp[1];
        }
        {
          int ch = tid;
#pragma unroll
          for (int u = 0; u < 8; ++u, ch += 256) {       // B: 64 rows x 256 k, L2
            int r = ch >> 5, cc = (ch & 31) * 8;
            *(u32x4v*)&sB[r * LSTRA + cc] = *(const u32x4v*)(W2B + r * HID + k0 + cc);
          }
        }
        __syncthreads();
#pragma unroll
        for (int ks = 0; ks < 8; ++ks) {
          bf16x8 af  = *(bf16x8*)&sA[al * LSTRA + ks * 32 + koff];
          bf16x8 bf_ = *(bf16x8*)&sB[(wv * 16 + al) * LSTRA + ks * 32 + koff];
          lg = MFMA16(af, bf_, lg, 0, 0, 0);
        }
      }
      float vraw[4], ev[4];
#pragma unroll
      for (int i = 0; i < 4; ++i) {
        float v = lg[i] + b2v;
        vraw[i] = v;
        float c = fminf(10.f, fmaxf(-10.f, v));
        ev[i] = __expf(c);
        sE[(q * 4 + i) * 68 + (wv * 16 + al)] = ev[i];
      }
      __syncthreads();
      if (tid < 16) {
        const float* row = &sE[tid * 68];
        float sm = 0.f;
        for (int k = 0; k < 64; ++k) sm += row[k];
        sInv[tid] = 1.f / sm;
      }
      __syncthreads();
      const int col = wv * 16 + al;
      unsigned short* sb = sbuf + (s & 1) * (Bb * Kk);
#pragma unroll
      for (int i = 0; i < 4; ++i) {
        int row16 = q * 4 + i;
        int grow = r0 + row16;
        dout[grow * (Tt * Kk) + s * Kk + col] = vraw[i];
        sb[grow * Kk + col] = f2bf(ev[i] * sInv[row16]);
      }
      rel_add(CTR(4));
    }
  }
}

__global__ void __launch_bounds__(256, 1)
seqkern(const float* ctx, const float* init_state, const float* b_ih, const float* b_hh,
        const float* b1, const float* b2, float* dout,
        const unsigned short* WhhB, const unsigned short* WXB, const unsigned short* W1B,
        const unsigned short* W2B, const unsigned short* MtB,
        float* h32, unsigned short* hbf, float* gix, unsigned short* xbf,
        unsigned short* abf, unsigned short* sbuf, int* ctrl) {
  extern __shared__ char smem[];
  unsigned short* sA = (unsigned short*)smem;                   // 128*264*2 = 67584
  unsigned short* sB = (unsigned short*)(smem + 67584);         // 64*264*2  = 33792
  unsigned short* sS = (unsigned short*)(smem + 101376);        // 9216
  const int bid = blockIdx.x;
  if (bid < 128)
    a_main(bid, init_state, b_ih, b_hh, WhhB, MtB, h32, hbf, gix, sbuf, ctrl, sA, sB, sS);
  else if (bid < 192)
    x_main(bid - 128, ctx, xbf, WXB, gix, ctrl, sA, sB);
  else
    al_main(bid - 192, hbf, W1B, W2B, b1, b2, abf, sbuf, dout, ctrl, sA, sB, sS);
}

extern "C" void kernel_launch(void* const* d_in, const int* in_sizes, int n_in,
                              void* d_out, int out_size, void* d_ws, size_t ws_size,
                              hipStream_t stream) {
  const float* ctx        = (const float*)d_in[0];
  const float* init_state = (const float*)d_in[1];
  const float* E          = (const float*)d_in[2];
  const float* Wih        = (const float*)d_in[3];
  const float* Whh        = (const float*)d_in[4];
  const float* b_ih       = (const float*)d_in[5];
  const float* b_hh       = (const float*)d_in[6];
  const float* W1         = (const float*)d_in[7];
  const float* b1         = (const float*)d_in[8];
  const float* W2         = (const float*)d_in[9];
  const float* b2         = (const float*)d_in[10];
  float* out = (float*)d_out;
  (void)in_sizes; (void)n_in; (void)out_size; (void)ws_size;

  char* ws = (char*)d_ws;
  size_t off = 0;
  auto take = [&](size_t sz) { char* p = ws + off; off += (sz + 255) & ~(size_t)255; return p; };
  int* ctrl             = (int*)take(1024);
  unsigned short* WhhB  = (unsigned short*)take((size_t)G3 * Hh * 2);
  unsigned short* WXB   = (unsigned short*)take((size_t)G3 * Hh * 2);
  unsigned short* W1B   = (unsigned short*)take((size_t)HID * Hh * 2);
  unsigned short* W2B   = (unsigned short*)take((size_t)Kk * HID * 2);
  unsigned short* MtB   = (unsigned short*)take((size_t)G3 * Kk * 2);
  float* h32            = (float*)take((size_t)2 * Bb * Hh * 4);
  unsigned short* hbf   = (unsigned short*)take((size_t)2 * Bb * Hh * 2);
  float* gix            = (float*)take((size_t)2 * Bb * G3 * 4);
  unsigned short* xbf   = (unsigned short*)take((size_t)2 * Bb * Hh * 2);
  unsigned short* abf   = (unsigned short*)take((size_t)2 * Bb * HID * 2);
  unsigned short* sbuf  = (unsigned short*)take((size_t)2 * Bb * Kk * 2);

  hipMemsetAsync(ctrl, 0, 1024, stream);
  hipLaunchKernelGGL(prep_convert, dim3(2048), dim3(256), 0, stream,
                     Whh, Wih, W1, W2, WhhB, WXB, W1B, W2B);
  hipLaunchKernelGGL(prep_mt, dim3(768), dim3(256), 0, stream, Wih, E, MtB);

  static int smem_set = 0;
  if (!smem_set) {
    hipFuncSetAttribute((const void*)seqkern,
                        hipFuncAttributeMaxDynamicSharedMemorySize, 110592);
    smem_set = 1;
  }
  void* args[] = {(void*)&ctx, (void*)&init_state, (void*)&b_ih, (void*)&b_hh,
                  (void*)&b1, (void*)&b2, (void*)&out,
                  (void*)&WhhB, (void*)&WXB, (void*)&W1B, (void*)&W2B, (void*)&MtB,
                  (void*)&h32, (void*)&hbf, (void*)&gix, (void*)&xbf,
                  (void*)&abf, (void*)&sbuf, (void*)&ctrl};
  hipLaunchCooperativeKernel((const void*)seqkern, dim3(256), dim3(256), args, 110592, stream);
}